// Round 7
// baseline (232.994 us; speedup 1.0000x reference)
//
#include <hip/hip_runtime.h>
#include <math.h>

typedef int i32x4 __attribute__((ext_vector_type(4)));
typedef int i32x16 __attribute__((ext_vector_type(16)));

#define NT_M 128   // T/64
#define NT_D 32    // D/64
#define NT_F 22    // F/64
#define DDIM 2048
#define FDIM 1408

// Swizzled byte offset of element (r,k) inside a 64x64 i8 tile.
#define OFFSWZ(r, k) (((r) << 6) + ((((((k) >> 4)) + ((r) >> 1)) & 3) << 4) + ((k) & 15))

// Counted vector-memory wait: never drain to 0 in the main loop (T4).
#define WAITVM(N) asm volatile("s_waitcnt vmcnt(%0)" ::"n"(N) : "memory")

__device__ __forceinline__ void gld_lds16(const void* gp, void* lp) {
  auto* l = reinterpret_cast<unsigned int __attribute__((address_space(3)))*>(
      (unsigned int)(unsigned long long)(lp));
  const auto* g = reinterpret_cast<const unsigned int __attribute__((address_space(1)))*>(
      (unsigned long long)(gp));
  __builtin_amdgcn_global_load_lds(g, l, 16, 0, 0);
}

__device__ __forceinline__ i32x16 zero16() {
  i32x16 z;
#pragma unroll
  for (int e = 0; e < 16; ++e) z[e] = 0;
  return z;
}

// ---------------- pack x into 3 signed base-256 digit planes, tiled+swizzled ----------------
__global__ __launch_bounds__(256) void pack_x_kernel(const int* __restrict__ x,
                                                     signed char* __restrict__ XD) {
  const int tk = blockIdx.x;   // 0..31   (D tiles)
  const int tm = blockIdx.y;   // 0..127  (T tiles)
  const int tid = threadIdx.x;
  signed char* tile = XD + (size_t)(tm * NT_D + tk) * 3 * 4096;
  const int* base = x + (size_t)tm * 64 * DDIM + tk * 64;
#pragma unroll
  for (int i = 0; i < 4; ++i) {
    const int gi = i * 256 + tid;      // 1024 groups of 4 elements
    const int row = gi >> 4;           // 64 rows
    const int k4 = (gi & 15) << 2;     // k offset, multiple of 4
    const i32x4 v = *(const i32x4*)(base + (size_t)row * DDIM + k4);
    unsigned p0 = 0, p1 = 0, p2 = 0;
#pragma unroll
    for (int j = 0; j < 4; ++j) {
      const int val = v[j];
      const int b0 = (int)(signed char)(val & 0xff);
      const int c = (val - b0) >> 8;
      const int b1 = (int)(signed char)(c & 0xff);
      const int b2 = (c - b1) >> 8;
      p0 |= ((unsigned)(val & 0xff)) << (8 * j);
      p1 |= ((unsigned)(c & 0xff)) << (8 * j);
      p2 |= ((unsigned)(b2 & 0xff)) << (8 * j);
    }
    const int off = OFFSWZ(row, k4);
    *(unsigned*)(tile + off) = p0;
    *(unsigned*)(tile + 4096 + off) = p1;
    *(unsigned*)(tile + 8192 + off) = p2;
  }
}

// ---------------- pack w1/w3/w2 (int32 holding i8 values) into i8 tiles ----------------
__global__ __launch_bounds__(256) void pack_w_kernel(const int* __restrict__ w1,
                                                     const int* __restrict__ w3,
                                                     const int* __restrict__ w2,
                                                     signed char* __restrict__ W1T,
                                                     signed char* __restrict__ W3T,
                                                     signed char* __restrict__ W2T) {
  const int which = blockIdx.y;   // 0=w1, 1=w3, 2=w2
  const int t = blockIdx.x;       // 704 tiles each
  const int tid = threadIdx.x;
  const int* src;
  signed char* dst;
  int rowstride, nk;
  if (which == 0)      { src = w1; dst = W1T; rowstride = DDIM; nk = NT_D; }
  else if (which == 1) { src = w3; dst = W3T; rowstride = DDIM; nk = NT_D; }
  else                 { src = w2; dst = W2T; rowstride = FDIM; nk = NT_F; }
  const int tr = t / nk, tk = t % nk;
  signed char* tile = dst + (size_t)t * 4096;
  const int* base = src + (size_t)tr * 64 * rowstride + tk * 64;
#pragma unroll
  for (int i = 0; i < 4; ++i) {
    const int gi = i * 256 + tid;
    const int row = gi >> 4;
    const int k4 = (gi & 15) << 2;
    const i32x4 v = *(const i32x4*)(base + (size_t)row * rowstride + k4);
    const unsigned p = ((unsigned)(v[0] & 0xff)) | ((unsigned)(v[1] & 0xff) << 8) |
                       ((unsigned)(v[2] & 0xff) << 16) | ((unsigned)(v[3] & 0xff) << 24);
    *(unsigned*)(tile + OFFSWZ(row, k4)) = p;
  }
}

// ---------------- gemm1: 64x64 tile, 4 waves, 4-buffer counted-vmcnt pipeline ----------------
// r1=(x@w1^T)>>s1, r2=(x@w3^T)>>s3, gate=(silu_q23(r1)*r2)>>23  (exact int64 semantics)
__global__ __launch_bounds__(256, 2) void gemm1_kernel(
    const signed char* __restrict__ XD, const signed char* __restrict__ W1T,
    const signed char* __restrict__ W3T, signed char* __restrict__ GATE,
    const int* __restrict__ scale1p, const int* __restrict__ scale3p) {
  __shared__ __align__(16) signed char lds[81920];  // 4 bufs x (A 12288 + B 8192)
  const int tid = threadIdx.x;
  const int wv = tid >> 6;
  const int lane = tid & 63;
  const int r32 = lane & 31;
  const int g = lane >> 5;
  // XCD-grouping swizzle: all 22 tf-blocks of one tm land on the same XCD.
  const int bi = blockIdx.x;
  const int c = bi & 7;
  const int q = bi >> 3;            // 0..351
  const int tm = (q / 22) * 8 + c;  // 0..127
  const int tf = q % 22;            // 0..21
  const int wm = wv >> 1, wn = wv & 1;

  i32x16 acc10 = zero16(), acc11 = zero16(), acc12 = zero16();
  i32x16 acc30 = zero16(), acc31 = zero16(), acc32 = zero16();

  const signed char* srcAbase = XD + (size_t)tm * NT_D * 3 * 4096;
  const signed char* srcB1base = W1T + (size_t)tf * NT_D * 4096;
  const signed char* srcB3base = W3T + (size_t)tf * NT_D * 4096;

  auto stage = [&](int kt, int b) {
    signed char* buf = lds + b * 20480;
#pragma unroll
    for (int j = 0; j < 3; ++j) {
      const int ch = wv * 3 + j;  // 12 chunks of 1KB = 3 digit planes
      gld_lds16(srcAbase + (size_t)kt * 12288 + ch * 1024 + lane * 16, buf + ch * 1024);
    }
#pragma unroll
    for (int j = 0; j < 2; ++j) {
      const int ch = wv * 2 + j;  // 8 chunks: 0-3 = w1 tile, 4-7 = w3 tile
      const signed char* s = (ch < 4) ? srcB1base + (size_t)kt * 4096 + ch * 1024
                                      : srcB3base + (size_t)kt * 4096 + (ch - 4) * 1024;
      gld_lds16(s + lane * 16, buf + 12288 + ch * 1024);
    }
  };

  const int arow = wm * 32 + r32;
  const int brow = wn * 32 + r32;
  const int aoffbase = arow * 64;
  const int boffbase = brow * 64;
  const int ash = arow >> 1;
  const int bsh = brow >> 1;

  auto compute = [&](int b) {
    const signed char* A = lds + b * 20480;
    const signed char* B = lds + b * 20480 + 12288;
#pragma unroll
    for (int kk = 0; kk < 2; ++kk) {
      const int ks = kk * 2 + g;
      const int sa = (ks + ash) & 3;
      const int sb = (ks + bsh) & 3;
      const i32x4 a0 = *(const i32x4*)(A + aoffbase + sa * 16);
      const i32x4 a1 = *(const i32x4*)(A + 4096 + aoffbase + sa * 16);
      const i32x4 a2 = *(const i32x4*)(A + 8192 + aoffbase + sa * 16);
      const i32x4 bb1 = *(const i32x4*)(B + boffbase + sb * 16);
      const i32x4 bb3 = *(const i32x4*)(B + 4096 + boffbase + sb * 16);
      acc10 = __builtin_amdgcn_mfma_i32_32x32x32_i8(a0, bb1, acc10, 0, 0, 0);
      acc11 = __builtin_amdgcn_mfma_i32_32x32x32_i8(a1, bb1, acc11, 0, 0, 0);
      acc12 = __builtin_amdgcn_mfma_i32_32x32x32_i8(a2, bb1, acc12, 0, 0, 0);
      acc30 = __builtin_amdgcn_mfma_i32_32x32x32_i8(a0, bb3, acc30, 0, 0, 0);
      acc31 = __builtin_amdgcn_mfma_i32_32x32x32_i8(a1, bb3, acc31, 0, 0, 0);
      acc32 = __builtin_amdgcn_mfma_i32_32x32x32_i8(a2, bb3, acc32, 0, 0, 0);
    }
  };

  // Prologue: prefetch depth 3 (15 loads/thread outstanding).
  stage(0, 0);
  stage(1, 1);
  stage(2, 2);

  for (int kt = 0; kt < NT_D; ++kt) {
    const int b = kt & 3;
    if (kt < NT_D - 3) {
      WAITVM(10);  // tile kt landed; kt+1,kt+2 (2x5 loads) still in flight
      __builtin_amdgcn_s_barrier();
      __builtin_amdgcn_sched_barrier(0);
      // buf (kt+3)&3 == (kt-1)&3: all waves finished reading it before this barrier
      stage(kt + 3, (kt + 3) & 3);
    } else if (kt == NT_D - 3) {
      WAITVM(10);
      __builtin_amdgcn_s_barrier();
      __builtin_amdgcn_sched_barrier(0);
    } else if (kt == NT_D - 2) {
      WAITVM(5);
      __builtin_amdgcn_s_barrier();
      __builtin_amdgcn_sched_barrier(0);
    } else {
      WAITVM(0);
      __builtin_amdgcn_s_barrier();
      __builtin_amdgcn_sched_barrier(0);
    }
    compute(b);
  }

  const int s1v = scale1p[0];
  const int s3v = scale3p[0];
  signed char* gt = GATE + (size_t)(tm * NT_F + tf) * 4096;
  const int colf = wn * 32 + r32;
  const double QINV = 1.0 / 8388608.0;
#pragma unroll
  for (int e = 0; e < 16; ++e) {
    const int rowe = (e & 3) + 8 * (e >> 2) + 4 * g;
    const int ml = wm * 32 + rowe;
    const long long av1 =
        (long long)acc10[e] + ((long long)acc11[e] << 8) + ((long long)acc12[e] << 16);
    const long long r1 = av1 >> s1v;
    const long long av3 =
        (long long)acc30[e] + ((long long)acc31[e] << 8) + ((long long)acc32[e] << 16);
    const long long r2 = av3 >> s3v;
    const double xf = (double)r1 * QINV;
    const double t = exp(-fabs(xf));
    const double sg = (xf >= 0.0) ? (1.0 / (1.0 + t)) : (t / (1.0 + t));
    const long long s1q = (long long)rint((double)r1 * sg);
    const long long gv = (s1q * r2) >> 23;
    gt[OFFSWZ(ml, colf)] = (signed char)gv;
  }
}

// ---------------- gemm2: q = (gate @ w2^T) >> s2, int32 out; same pipeline ----------------
__global__ __launch_bounds__(256, 2) void gemm2_kernel(
    const signed char* __restrict__ GATE, const signed char* __restrict__ W2T,
    int* __restrict__ out, const int* __restrict__ scale2p) {
  __shared__ __align__(16) signed char lds[65536];  // 4 bufs x (A 8192 + B 8192)
  const int tid = threadIdx.x;
  const int wv = tid >> 6;
  const int lane = tid & 63;
  const int r32 = lane & 31;
  const int g = lane >> 5;
  // XCD-grouping swizzle: 1024 blocks = 8 XCDs * 8 tm * 16 tn
  const int bi = blockIdx.x;
  const int c = bi & 7;
  const int q = bi >> 3;           // 0..127
  const int tm = (q >> 4) * 8 + c; // 0..63 (T/128)
  const int tn = q & 15;           // 0..15 (D/128)
  const int wm = wv >> 1, wn = wv & 1;

  i32x16 acc00 = zero16(), acc01 = zero16(), acc10 = zero16(), acc11 = zero16();

  auto stage = [&](int kt, int b) {
    signed char* buf = lds + b * 16384;
#pragma unroll
    for (int j = 0; j < 2; ++j) {
      const int ch = wv * 2 + j;  // 8 chunks: 2 gate m-tiles
      gld_lds16(GATE + ((size_t)((tm * 2 + (ch >> 2)) * NT_F + kt)) * 4096 + (ch & 3) * 1024 +
                    lane * 16,
                buf + ch * 1024);
    }
#pragma unroll
    for (int j = 0; j < 2; ++j) {
      const int ch = wv * 2 + j;  // 8 chunks: 2 w2 d-tiles
      gld_lds16(W2T + ((size_t)((tn * 2 + (ch >> 2)) * NT_F + kt)) * 4096 + (ch & 3) * 1024 +
                    lane * 16,
                buf + 8192 + ch * 1024);
    }
  };

  const int r0 = r32, r1r = 32 + r32;
  const int s0b = r0 >> 1, s1b = r1r >> 1;

  auto compute = [&](int b) {
    const signed char* A = lds + b * 16384 + wm * 4096;
    const signed char* B = lds + b * 16384 + 8192 + wn * 4096;
#pragma unroll
    for (int kk = 0; kk < 2; ++kk) {
      const int ks = kk * 2 + g;
      const int sa0 = (ks + s0b) & 3;
      const int sa1 = (ks + s1b) & 3;
      const i32x4 a0 = *(const i32x4*)(A + r0 * 64 + sa0 * 16);
      const i32x4 a1 = *(const i32x4*)(A + r1r * 64 + sa1 * 16);
      const i32x4 b0 = *(const i32x4*)(B + r0 * 64 + sa0 * 16);
      const i32x4 b1 = *(const i32x4*)(B + r1r * 64 + sa1 * 16);
      acc00 = __builtin_amdgcn_mfma_i32_32x32x32_i8(a0, b0, acc00, 0, 0, 0);
      acc01 = __builtin_amdgcn_mfma_i32_32x32x32_i8(a0, b1, acc01, 0, 0, 0);
      acc10 = __builtin_amdgcn_mfma_i32_32x32x32_i8(a1, b0, acc10, 0, 0, 0);
      acc11 = __builtin_amdgcn_mfma_i32_32x32x32_i8(a1, b1, acc11, 0, 0, 0);
    }
  };

  stage(0, 0);
  stage(1, 1);
  stage(2, 2);

  for (int kt = 0; kt < NT_F; ++kt) {
    const int b = kt & 3;
    if (kt < NT_F - 3) {
      WAITVM(8);
      __builtin_amdgcn_s_barrier();
      __builtin_amdgcn_sched_barrier(0);
      stage(kt + 3, (kt + 3) & 3);
    } else if (kt == NT_F - 3) {
      WAITVM(8);
      __builtin_amdgcn_s_barrier();
      __builtin_amdgcn_sched_barrier(0);
    } else if (kt == NT_F - 2) {
      WAITVM(4);
      __builtin_amdgcn_s_barrier();
      __builtin_amdgcn_sched_barrier(0);
    } else {
      WAITVM(0);
      __builtin_amdgcn_s_barrier();
      __builtin_amdgcn_sched_barrier(0);
    }
    compute(b);
  }

  const int s2v = scale2p[0];
  int* obase = out + (size_t)(tm * 128 + wm * 64) * DDIM + tn * 128 + wn * 64;
#pragma unroll
  for (int e = 0; e < 16; ++e) {
    const int rowe = (e & 3) + 8 * (e >> 2) + 4 * g;
    obase[(size_t)rowe * DDIM + r32] = acc00[e] >> s2v;
    obase[(size_t)rowe * DDIM + 32 + r32] = acc01[e] >> s2v;
    obase[(size_t)(rowe + 32) * DDIM + r32] = acc10[e] >> s2v;
    obase[(size_t)(rowe + 32) * DDIM + 32 + r32] = acc11[e] >> s2v;
  }
}

extern "C" void kernel_launch(void* const* d_in, const int* in_sizes, int n_in,
                              void* d_out, int out_size, void* d_ws, size_t ws_size,
                              hipStream_t stream) {
  if (n_in < 7) return;
  const int* x = (const int*)d_in[0];
  const int* w1 = (const int*)d_in[1];
  const int* w2 = (const int*)d_in[2];
  const int* w3 = (const int*)d_in[3];
  const int* s1 = (const int*)d_in[4];
  const int* s2 = (const int*)d_in[5];
  const int* s3 = (const int*)d_in[6];
  signed char* ws = (signed char*)d_ws;
  int* out = (int*)d_out;

  const size_t XD_OFF = 0;
  const size_t XD_SZ = (size_t)NT_M * NT_D * 3 * 4096;   // 50331648
  const size_t WT_SZ = (size_t)NT_F * NT_D * 4096;       // 2883584
  const size_t W1_OFF = XD_OFF + XD_SZ;
  const size_t W3_OFF = W1_OFF + WT_SZ;
  const size_t W2_OFF = W3_OFF + WT_SZ;
  const size_t GATE_OFF = W2_OFF + WT_SZ;
  const size_t GATE_SZ = (size_t)NT_M * NT_F * 4096;     // 11534336
  if (ws_size < GATE_OFF + GATE_SZ) return;  // ~70.5 MB required

  pack_x_kernel<<<dim3(NT_D, NT_M), 256, 0, stream>>>(x, ws + XD_OFF);
  pack_w_kernel<<<dim3(704, 3), 256, 0, stream>>>(w1, w3, w2, ws + W1_OFF, ws + W3_OFF,
                                                  ws + W2_OFF);
  gemm1_kernel<<<dim3(2816), 256, 0, stream>>>(ws + XD_OFF, ws + W1_OFF, ws + W3_OFF,
                                               ws + GATE_OFF, s1, s3);
  gemm2_kernel<<<dim3(1024), 256, 0, stream>>>(ws + GATE_OFF, ws + W2_OFF, out, s2);
}

// Round 8
// 218.507 us; speedup vs baseline: 1.0663x; 1.0663x over previous
//
#include <hip/hip_runtime.h>
#include <math.h>

typedef int i32x4 __attribute__((ext_vector_type(4)));
typedef int i32x16 __attribute__((ext_vector_type(16)));

#define NT_M 128   // T/64
#define NT_D 32    // D/64
#define NT_F 22    // F/64
#define DDIM 2048
#define FDIM 1408

// Swizzled byte offset of element (r,k) inside a 64x64 i8 tile.
#define OFFSWZ(r, k) (((r) << 6) + ((((((k) >> 4)) + ((r) >> 1)) & 3) << 4) + ((k) & 15))

// Counted vector-memory wait: never drain to 0 in the main loop (T4).
#define WAITVM(N) asm volatile("s_waitcnt vmcnt(%0)" ::"n"(N) : "memory")

__device__ __forceinline__ void gld_lds16(const void* gp, void* lp) {
  auto* l = reinterpret_cast<unsigned int __attribute__((address_space(3)))*>(
      (unsigned int)(unsigned long long)(lp));
  const auto* g = reinterpret_cast<const unsigned int __attribute__((address_space(1)))*>(
      (unsigned long long)(gp));
  __builtin_amdgcn_global_load_lds(g, l, 16, 0, 0);
}

__device__ __forceinline__ i32x16 zero16() {
  i32x16 z;
#pragma unroll
  for (int e = 0; e < 16; ++e) z[e] = 0;
  return z;
}

// ---------------- pack x into 3 signed base-256 digit planes, tiled+swizzled ----------------
__global__ __launch_bounds__(256) void pack_x_kernel(const int* __restrict__ x,
                                                     signed char* __restrict__ XD) {
  const int tk = blockIdx.x;   // 0..31   (D tiles)
  const int tm = blockIdx.y;   // 0..127  (T tiles)
  const int tid = threadIdx.x;
  signed char* tile = XD + (size_t)(tm * NT_D + tk) * 3 * 4096;
  const int* base = x + (size_t)tm * 64 * DDIM + tk * 64;
#pragma unroll
  for (int i = 0; i < 4; ++i) {
    const int gi = i * 256 + tid;      // 1024 groups of 4 elements
    const int row = gi >> 4;           // 64 rows
    const int k4 = (gi & 15) << 2;     // k offset, multiple of 4
    const i32x4 v = *(const i32x4*)(base + (size_t)row * DDIM + k4);
    unsigned p0 = 0, p1 = 0, p2 = 0;
#pragma unroll
    for (int j = 0; j < 4; ++j) {
      const int val = v[j];
      const int b0 = (int)(signed char)(val & 0xff);
      const int c = (val - b0) >> 8;
      const int b1 = (int)(signed char)(c & 0xff);
      const int b2 = (c - b1) >> 8;
      p0 |= ((unsigned)(val & 0xff)) << (8 * j);
      p1 |= ((unsigned)(c & 0xff)) << (8 * j);
      p2 |= ((unsigned)(b2 & 0xff)) << (8 * j);
    }
    const int off = OFFSWZ(row, k4);
    *(unsigned*)(tile + off) = p0;
    *(unsigned*)(tile + 4096 + off) = p1;
    *(unsigned*)(tile + 8192 + off) = p2;
  }
}

// ---------------- pack w1/w3/w2 (int32 holding i8 values) into i8 tiles ----------------
__global__ __launch_bounds__(256) void pack_w_kernel(const int* __restrict__ w1,
                                                     const int* __restrict__ w3,
                                                     const int* __restrict__ w2,
                                                     signed char* __restrict__ W1T,
                                                     signed char* __restrict__ W3T,
                                                     signed char* __restrict__ W2T) {
  const int which = blockIdx.y;   // 0=w1, 1=w3, 2=w2
  const int t = blockIdx.x;       // 704 tiles each
  const int tid = threadIdx.x;
  const int* src;
  signed char* dst;
  int rowstride, nk;
  if (which == 0)      { src = w1; dst = W1T; rowstride = DDIM; nk = NT_D; }
  else if (which == 1) { src = w3; dst = W3T; rowstride = DDIM; nk = NT_D; }
  else                 { src = w2; dst = W2T; rowstride = FDIM; nk = NT_F; }
  const int tr = t / nk, tk = t % nk;
  signed char* tile = dst + (size_t)t * 4096;
  const int* base = src + (size_t)tr * 64 * rowstride + tk * 64;
#pragma unroll
  for (int i = 0; i < 4; ++i) {
    const int gi = i * 256 + tid;
    const int row = gi >> 4;
    const int k4 = (gi & 15) << 2;
    const i32x4 v = *(const i32x4*)(base + (size_t)row * rowstride + k4);
    const unsigned p = ((unsigned)(v[0] & 0xff)) | ((unsigned)(v[1] & 0xff) << 8) |
                       ((unsigned)(v[2] & 0xff) << 16) | ((unsigned)(v[3] & 0xff) << 24);
    *(unsigned*)(tile + OFFSWZ(row, k4)) = p;
  }
}

// ---------------- gemm1: 64x64 tile, 4 waves, 3-buffer counted-vmcnt pipeline ----------------
// r1=(x@w1^T)>>s1, r2=(x@w3^T)>>s3, gate=(silu_q23(r1)*r2)>>23  (exact int64 semantics)
__global__ __launch_bounds__(256, 2) void gemm1_kernel(
    const signed char* __restrict__ XD, const signed char* __restrict__ W1T,
    const signed char* __restrict__ W3T, signed char* __restrict__ GATE,
    const int* __restrict__ scale1p, const int* __restrict__ scale3p) {
  __shared__ __align__(16) signed char lds[61440];  // 3 bufs x (A 12288 + B 8192)
  const int tid = threadIdx.x;
  const int wv = tid >> 6;
  const int lane = tid & 63;
  const int r32 = lane & 31;
  const int g = lane >> 5;
  // XCD-grouping swizzle: all 22 tf-blocks of one tm land on the same XCD.
  const int bi = blockIdx.x;
  const int c = bi & 7;
  const int q = bi >> 3;            // 0..351
  const int tm = (q / 22) * 8 + c;  // 0..127
  const int tf = q % 22;            // 0..21
  const int wm = wv >> 1, wn = wv & 1;

  i32x16 acc10 = zero16(), acc11 = zero16(), acc12 = zero16();
  i32x16 acc30 = zero16(), acc31 = zero16(), acc32 = zero16();

  const signed char* srcAbase = XD + (size_t)tm * NT_D * 3 * 4096;
  const signed char* srcB1base = W1T + (size_t)tf * NT_D * 4096;
  const signed char* srcB3base = W3T + (size_t)tf * NT_D * 4096;

  auto stage = [&](int kt, int b) {
    signed char* buf = lds + b * 20480;
#pragma unroll
    for (int j = 0; j < 3; ++j) {
      const int ch = wv * 3 + j;  // 12 chunks of 1KB = 3 digit planes
      gld_lds16(srcAbase + (size_t)kt * 12288 + ch * 1024 + lane * 16, buf + ch * 1024);
    }
#pragma unroll
    for (int j = 0; j < 2; ++j) {
      const int ch = wv * 2 + j;  // 8 chunks: 0-3 = w1 tile, 4-7 = w3 tile
      const signed char* s = (ch < 4) ? srcB1base + (size_t)kt * 4096 + ch * 1024
                                      : srcB3base + (size_t)kt * 4096 + (ch - 4) * 1024;
      gld_lds16(s + lane * 16, buf + 12288 + ch * 1024);
    }
  };

  const int arow = wm * 32 + r32;
  const int brow = wn * 32 + r32;
  const int aoffbase = arow * 64;
  const int boffbase = brow * 64;
  const int ash = arow >> 1;
  const int bsh = brow >> 1;

  auto compute = [&](int b) {
    const signed char* A = lds + b * 20480;
    const signed char* B = lds + b * 20480 + 12288;
#pragma unroll
    for (int kk = 0; kk < 2; ++kk) {
      const int ks = kk * 2 + g;
      const int sa = (ks + ash) & 3;
      const int sb = (ks + bsh) & 3;
      const i32x4 a0 = *(const i32x4*)(A + aoffbase + sa * 16);
      const i32x4 a1 = *(const i32x4*)(A + 4096 + aoffbase + sa * 16);
      const i32x4 a2 = *(const i32x4*)(A + 8192 + aoffbase + sa * 16);
      const i32x4 bb1 = *(const i32x4*)(B + boffbase + sb * 16);
      const i32x4 bb3 = *(const i32x4*)(B + 4096 + boffbase + sb * 16);
      acc10 = __builtin_amdgcn_mfma_i32_32x32x32_i8(a0, bb1, acc10, 0, 0, 0);
      acc11 = __builtin_amdgcn_mfma_i32_32x32x32_i8(a1, bb1, acc11, 0, 0, 0);
      acc12 = __builtin_amdgcn_mfma_i32_32x32x32_i8(a2, bb1, acc12, 0, 0, 0);
      acc30 = __builtin_amdgcn_mfma_i32_32x32x32_i8(a0, bb3, acc30, 0, 0, 0);
      acc31 = __builtin_amdgcn_mfma_i32_32x32x32_i8(a1, bb3, acc31, 0, 0, 0);
      acc32 = __builtin_amdgcn_mfma_i32_32x32x32_i8(a2, bb3, acc32, 0, 0, 0);
    }
  };

  // Prologue: prefetch depth 2 (10 loads/thread outstanding).
  stage(0, 0);
  stage(1, 1);

  for (int kt = 0; kt < NT_D; ++kt) {
    if (kt + 2 < NT_D) {
      WAITVM(5);  // tile kt landed; kt+1 (5 loads) still in flight
      __builtin_amdgcn_s_barrier();
      __builtin_amdgcn_sched_barrier(0);
      // buf (kt+2)%3 == (kt-1)%3: every wave consumed it in iter kt-1, before this barrier
      stage(kt + 2, (kt + 2) % 3);
    } else if (kt + 2 == NT_D) {
      WAITVM(5);
      __builtin_amdgcn_s_barrier();
      __builtin_amdgcn_sched_barrier(0);
    } else {
      WAITVM(0);
      __builtin_amdgcn_s_barrier();
      __builtin_amdgcn_sched_barrier(0);
    }
    compute(kt % 3);
  }

  const int s1v = scale1p[0];
  const int s3v = scale3p[0];
  signed char* gt = GATE + (size_t)(tm * NT_F + tf) * 4096;
  const int colf = wn * 32 + r32;
  const double QINV = 1.0 / 8388608.0;
#pragma unroll
  for (int e = 0; e < 16; ++e) {
    const int rowe = (e & 3) + 8 * (e >> 2) + 4 * g;
    const int ml = wm * 32 + rowe;
    const long long av1 =
        (long long)acc10[e] + ((long long)acc11[e] << 8) + ((long long)acc12[e] << 16);
    const long long r1 = av1 >> s1v;
    const long long av3 =
        (long long)acc30[e] + ((long long)acc31[e] << 8) + ((long long)acc32[e] << 16);
    const long long r2 = av3 >> s3v;
    // Exact silu: |r1| <= 2^14 so |xf| <= 2^-9; sigma(xf) = 0.5 + xf/4 - xf^3/48,
    // truncation < 6e-17 (< 1 ulp of 0.5) -- same accuracy class as the libm exp
    // path that matched the fp64 reference bit-exactly (rint margin ~4e-8).
    const double xf = (double)r1 * QINV;
    const double x2 = xf * xf;
    const double sg = 0.5 + xf * (0.25 - x2 * (1.0 / 48.0));
    const long long s1q = (long long)rint((double)r1 * sg);
    const long long gv = (s1q * r2) >> 23;
    gt[OFFSWZ(ml, colf)] = (signed char)gv;
  }
}

// ---------------- gemm2: q = (gate @ w2^T) >> s2, int32 out; 3-buffer pipeline ----------------
__global__ __launch_bounds__(256, 2) void gemm2_kernel(
    const signed char* __restrict__ GATE, const signed char* __restrict__ W2T,
    int* __restrict__ out, const int* __restrict__ scale2p) {
  __shared__ __align__(16) signed char lds[49152];  // 3 bufs x (A 8192 + B 8192)
  const int tid = threadIdx.x;
  const int wv = tid >> 6;
  const int lane = tid & 63;
  const int r32 = lane & 31;
  const int g = lane >> 5;
  // XCD-grouping swizzle: 1024 blocks = 8 XCDs * 8 tm * 16 tn
  const int bi = blockIdx.x;
  const int c = bi & 7;
  const int q = bi >> 3;           // 0..127
  const int tm = (q >> 4) * 8 + c; // 0..63 (T/128)
  const int tn = q & 15;           // 0..15 (D/128)
  const int wm = wv >> 1, wn = wv & 1;

  i32x16 acc00 = zero16(), acc01 = zero16(), acc10 = zero16(), acc11 = zero16();

  auto stage = [&](int kt, int b) {
    signed char* buf = lds + b * 16384;
#pragma unroll
    for (int j = 0; j < 2; ++j) {
      const int ch = wv * 2 + j;  // 8 chunks: 2 gate m-tiles
      gld_lds16(GATE + ((size_t)((tm * 2 + (ch >> 2)) * NT_F + kt)) * 4096 + (ch & 3) * 1024 +
                    lane * 16,
                buf + ch * 1024);
    }
#pragma unroll
    for (int j = 0; j < 2; ++j) {
      const int ch = wv * 2 + j;  // 8 chunks: 2 w2 d-tiles
      gld_lds16(W2T + ((size_t)((tn * 2 + (ch >> 2)) * NT_F + kt)) * 4096 + (ch & 3) * 1024 +
                    lane * 16,
                buf + 8192 + ch * 1024);
    }
  };

  const int r0 = r32, r1r = 32 + r32;
  const int s0b = r0 >> 1, s1b = r1r >> 1;

  auto compute = [&](int b) {
    const signed char* A = lds + b * 16384 + wm * 4096;
    const signed char* B = lds + b * 16384 + 8192 + wn * 4096;
#pragma unroll
    for (int kk = 0; kk < 2; ++kk) {
      const int ks = kk * 2 + g;
      const int sa0 = (ks + s0b) & 3;
      const int sa1 = (ks + s1b) & 3;
      const i32x4 a0 = *(const i32x4*)(A + r0 * 64 + sa0 * 16);
      const i32x4 a1 = *(const i32x4*)(A + r1r * 64 + sa1 * 16);
      const i32x4 b0 = *(const i32x4*)(B + r0 * 64 + sa0 * 16);
      const i32x4 b1 = *(const i32x4*)(B + r1r * 64 + sa1 * 16);
      acc00 = __builtin_amdgcn_mfma_i32_32x32x32_i8(a0, b0, acc00, 0, 0, 0);
      acc01 = __builtin_amdgcn_mfma_i32_32x32x32_i8(a0, b1, acc01, 0, 0, 0);
      acc10 = __builtin_amdgcn_mfma_i32_32x32x32_i8(a1, b0, acc10, 0, 0, 0);
      acc11 = __builtin_amdgcn_mfma_i32_32x32x32_i8(a1, b1, acc11, 0, 0, 0);
    }
  };

  stage(0, 0);
  stage(1, 1);

  for (int kt = 0; kt < NT_F; ++kt) {
    if (kt + 2 < NT_F) {
      WAITVM(4);
      __builtin_amdgcn_s_barrier();
      __builtin_amdgcn_sched_barrier(0);
      stage(kt + 2, (kt + 2) % 3);
    } else if (kt + 2 == NT_F) {
      WAITVM(4);
      __builtin_amdgcn_s_barrier();
      __builtin_amdgcn_sched_barrier(0);
    } else {
      WAITVM(0);
      __builtin_amdgcn_s_barrier();
      __builtin_amdgcn_sched_barrier(0);
    }
    compute(kt % 3);
  }

  const int s2v = scale2p[0];
  int* obase = out + (size_t)(tm * 128 + wm * 64) * DDIM + tn * 128 + wn * 64;
#pragma unroll
  for (int e = 0; e < 16; ++e) {
    const int rowe = (e & 3) + 8 * (e >> 2) + 4 * g;
    obase[(size_t)rowe * DDIM + r32] = acc00[e] >> s2v;
    obase[(size_t)rowe * DDIM + 32 + r32] = acc01[e] >> s2v;
    obase[(size_t)(rowe + 32) * DDIM + r32] = acc10[e] >> s2v;
    obase[(size_t)(rowe + 32) * DDIM + 32 + r32] = acc11[e] >> s2v;
  }
}

extern "C" void kernel_launch(void* const* d_in, const int* in_sizes, int n_in,
                              void* d_out, int out_size, void* d_ws, size_t ws_size,
                              hipStream_t stream) {
  if (n_in < 7) return;
  const int* x = (const int*)d_in[0];
  const int* w1 = (const int*)d_in[1];
  const int* w2 = (const int*)d_in[2];
  const int* w3 = (const int*)d_in[3];
  const int* s1 = (const int*)d_in[4];
  const int* s2 = (const int*)d_in[5];
  const int* s3 = (const int*)d_in[6];
  signed char* ws = (signed char*)d_ws;
  int* out = (int*)d_out;

  const size_t XD_OFF = 0;
  const size_t XD_SZ = (size_t)NT_M * NT_D * 3 * 4096;   // 50331648
  const size_t WT_SZ = (size_t)NT_F * NT_D * 4096;       // 2883584
  const size_t W1_OFF = XD_OFF + XD_SZ;
  const size_t W3_OFF = W1_OFF + WT_SZ;
  const size_t W2_OFF = W3_OFF + WT_SZ;
  const size_t GATE_OFF = W2_OFF + WT_SZ;
  const size_t GATE_SZ = (size_t)NT_M * NT_F * 4096;     // 11534336
  if (ws_size < GATE_OFF + GATE_SZ) return;  // ~70.5 MB required

  pack_x_kernel<<<dim3(NT_D, NT_M), 256, 0, stream>>>(x, ws + XD_OFF);
  pack_w_kernel<<<dim3(704, 3), 256, 0, stream>>>(w1, w3, w2, ws + W1_OFF, ws + W3_OFF,
                                                  ws + W2_OFF);
  gemm1_kernel<<<dim3(2816), 256, 0, stream>>>(ws + XD_OFF, ws + W1_OFF, ws + W3_OFF,
                                               ws + GATE_OFF, s1, s3);
  gemm2_kernel<<<dim3(1024), 256, 0, stream>>>(ws + GATE_OFF, ws + W2_OFF, out, s2);
}

// Round 9
// 193.243 us; speedup vs baseline: 1.2057x; 1.1307x over previous
//
#include <hip/hip_runtime.h>
#include <math.h>

typedef int i32x4 __attribute__((ext_vector_type(4)));
typedef int i32x16 __attribute__((ext_vector_type(16)));

#define NT_M 128   // T/64
#define NT_D 32    // D/64
#define NT_F 22    // F/64
#define DDIM 2048
#define FDIM 1408

// Fragment-order byte offset of element (r,k) in a 64x64 i8 tile (4096B).
// Layout = [k-block(2)][row-half(2)][k-halfword(2)][row%32(32)][k%16(16)]
// so an MFMA fragment read is base + kkblk*2048 + rowhalf*1024 + lane*16:
// canonical stride-16 per lane -> zero bank conflicts, and staging stays linear.
#define OFFN(r, k)                                                                  \
  (((((k) >> 5)) << 11) + ((((r) >> 5)) << 10) + (((((k) >> 4) & 1)) << 9) +        \
   ((((r) & 31)) << 4) + ((k) & 15))

__device__ __forceinline__ void gld_lds16(const void* gp, void* lp) {
  auto* l = reinterpret_cast<unsigned int __attribute__((address_space(3)))*>(
      (unsigned int)(unsigned long long)(lp));
  const auto* g = reinterpret_cast<const unsigned int __attribute__((address_space(1)))*>(
      (unsigned long long)(gp));
  __builtin_amdgcn_global_load_lds(g, l, 16, 0, 0);
}

__device__ __forceinline__ i32x16 zero16() {
  i32x16 z;
#pragma unroll
  for (int e = 0; e < 16; ++e) z[e] = 0;
  return z;
}

// ---------------- pack x into 3 signed base-256 digit planes, fragment-order tiles ----------------
__global__ __launch_bounds__(256) void pack_x_kernel(const int* __restrict__ x,
                                                     signed char* __restrict__ XD) {
  const int tk = blockIdx.x;   // 0..31   (D tiles)
  const int tm = blockIdx.y;   // 0..127  (T tiles)
  const int tid = threadIdx.x;
  signed char* tile = XD + (size_t)(tm * NT_D + tk) * 3 * 4096;
  const int* base = x + (size_t)tm * 64 * DDIM + tk * 64;
#pragma unroll
  for (int i = 0; i < 4; ++i) {
    const int gi = i * 256 + tid;      // 1024 groups of 4 elements
    const int row = gi >> 4;           // 64 rows
    const int k4 = (gi & 15) << 2;     // k offset, multiple of 4
    const i32x4 v = *(const i32x4*)(base + (size_t)row * DDIM + k4);
    unsigned p0 = 0, p1 = 0, p2 = 0;
#pragma unroll
    for (int j = 0; j < 4; ++j) {
      const int val = v[j];
      const int b0 = (int)(signed char)(val & 0xff);
      const int c = (val - b0) >> 8;
      const int b1 = (int)(signed char)(c & 0xff);
      const int b2 = (c - b1) >> 8;
      p0 |= ((unsigned)(val & 0xff)) << (8 * j);
      p1 |= ((unsigned)(c & 0xff)) << (8 * j);
      p2 |= ((unsigned)(b2 & 0xff)) << (8 * j);
    }
    const int off = OFFN(row, k4);
    *(unsigned*)(tile + off) = p0;
    *(unsigned*)(tile + 4096 + off) = p1;
    *(unsigned*)(tile + 8192 + off) = p2;
  }
}

// ---------------- pack w1/w3/w2 (int32 holding i8 values) into fragment-order tiles ----------------
__global__ __launch_bounds__(256) void pack_w_kernel(const int* __restrict__ w1,
                                                     const int* __restrict__ w3,
                                                     const int* __restrict__ w2,
                                                     signed char* __restrict__ W1T,
                                                     signed char* __restrict__ W3T,
                                                     signed char* __restrict__ W2T) {
  const int which = blockIdx.y;   // 0=w1, 1=w3, 2=w2
  const int t = blockIdx.x;       // 704 tiles each
  const int tid = threadIdx.x;
  const int* src;
  signed char* dst;
  int rowstride, nk;
  if (which == 0)      { src = w1; dst = W1T; rowstride = DDIM; nk = NT_D; }
  else if (which == 1) { src = w3; dst = W3T; rowstride = DDIM; nk = NT_D; }
  else                 { src = w2; dst = W2T; rowstride = FDIM; nk = NT_F; }
  const int tr = t / nk, tk = t % nk;
  signed char* tile = dst + (size_t)t * 4096;
  const int* base = src + (size_t)tr * 64 * rowstride + tk * 64;
#pragma unroll
  for (int i = 0; i < 4; ++i) {
    const int gi = i * 256 + tid;
    const int row = gi >> 4;
    const int k4 = (gi & 15) << 2;
    const i32x4 v = *(const i32x4*)(base + (size_t)row * rowstride + k4);
    const unsigned p = ((unsigned)(v[0] & 0xff)) | ((unsigned)(v[1] & 0xff) << 8) |
                       ((unsigned)(v[2] & 0xff) << 16) | ((unsigned)(v[3] & 0xff) << 24);
    *(unsigned*)(tile + OFFN(row, k4)) = p;
  }
}

// ---------------- gemm1: 64x64 tile, 4 waves, 2-buf LDS, conflict-free fragment reads ----------------
// r1=(x@w1^T)>>s1, r2=(x@w3^T)>>s3, gate=(silu_q23(r1)*r2)>>23  (exact int64 semantics)
__global__ __launch_bounds__(256, 2) void gemm1_kernel(
    const signed char* __restrict__ XD, const signed char* __restrict__ W1T,
    const signed char* __restrict__ W3T, signed char* __restrict__ GATE,
    const int* __restrict__ scale1p, const int* __restrict__ scale3p) {
  __shared__ __align__(16) signed char lds[40960];  // 2 bufs x (A 12288 + B 8192)
  const int tid = threadIdx.x;
  const int wv = tid >> 6;
  const int lane = tid & 63;
  const int r32 = lane & 31;
  const int g = lane >> 5;
  // XCD-grouping swizzle: all 22 tf-blocks of one tm land on the same XCD.
  const int bi = blockIdx.x;
  const int c = bi & 7;
  const int q = bi >> 3;            // 0..351
  const int tm = (q / 22) * 8 + c;  // 0..127
  const int tf = q % 22;            // 0..21
  const int wm = wv >> 1, wn = wv & 1;

  i32x16 acc10 = zero16(), acc11 = zero16(), acc12 = zero16();
  i32x16 acc30 = zero16(), acc31 = zero16(), acc32 = zero16();

  const signed char* srcAbase = XD + (size_t)tm * NT_D * 3 * 4096;
  const signed char* srcB1base = W1T + (size_t)tf * NT_D * 4096;
  const signed char* srcB3base = W3T + (size_t)tf * NT_D * 4096;

  auto stage = [&](int kt, int b) {
    signed char* buf = lds + b * 20480;
#pragma unroll
    for (int j = 0; j < 3; ++j) {
      const int ch = wv * 3 + j;  // 12 chunks of 1KB = 3 digit planes
      gld_lds16(srcAbase + (size_t)kt * 12288 + ch * 1024 + lane * 16, buf + ch * 1024);
    }
#pragma unroll
    for (int j = 0; j < 2; ++j) {
      const int ch = wv * 2 + j;  // 8 chunks: 0-3 = w1 tile, 4-7 = w3 tile
      const signed char* s = (ch < 4) ? srcB1base + (size_t)kt * 4096 + ch * 1024
                                      : srcB3base + (size_t)kt * 4096 + (ch - 4) * 1024;
      gld_lds16(s + lane * 16, buf + 12288 + ch * 1024);
    }
  };

  // Canonical fragment addresses: base + kk*2048 + half*1024 + lane*16 (stride-16/lane).
  const int aoff = (wm << 10) + lane * 16;
  const int boff = (wn << 10) + lane * 16;

  auto compute = [&](int b) {
    const signed char* A = lds + b * 20480;
    const signed char* B = lds + b * 20480 + 12288;
#pragma unroll
    for (int kk = 0; kk < 2; ++kk) {
      const int ko = kk * 2048;
      const i32x4 a0 = *(const i32x4*)(A + ko + aoff);
      const i32x4 a1 = *(const i32x4*)(A + 4096 + ko + aoff);
      const i32x4 a2 = *(const i32x4*)(A + 8192 + ko + aoff);
      const i32x4 bb1 = *(const i32x4*)(B + ko + boff);
      const i32x4 bb3 = *(const i32x4*)(B + 4096 + ko + boff);
      acc10 = __builtin_amdgcn_mfma_i32_32x32x32_i8(a0, bb1, acc10, 0, 0, 0);
      acc11 = __builtin_amdgcn_mfma_i32_32x32x32_i8(a1, bb1, acc11, 0, 0, 0);
      acc12 = __builtin_amdgcn_mfma_i32_32x32x32_i8(a2, bb1, acc12, 0, 0, 0);
      acc30 = __builtin_amdgcn_mfma_i32_32x32x32_i8(a0, bb3, acc30, 0, 0, 0);
      acc31 = __builtin_amdgcn_mfma_i32_32x32x32_i8(a1, bb3, acc31, 0, 0, 0);
      acc32 = __builtin_amdgcn_mfma_i32_32x32x32_i8(a2, bb3, acc32, 0, 0, 0);
    }
  };

  stage(0, 0);

  for (int kt = 0; kt < NT_D; ++kt) {
    const int b = kt & 1;
    __syncthreads();  // drains vmcnt(0): buffer b ready
    if (kt + 1 < NT_D) stage(kt + 1, b ^ 1);
    compute(b);
  }

  const int s1v = scale1p[0];
  const int s3v = scale3p[0];
  signed char* gt = GATE + (size_t)(tm * NT_F + tf) * 4096;
  const double QINV = 1.0 / 8388608.0;
  // OFFN(ml, colf) with ml = wm*32+rowe, colf = wn*32+r32:
  const int ebase = (wn << 11) + (wm << 10) + ((r32 >> 4) << 9) + (r32 & 15);
#pragma unroll
  for (int e = 0; e < 16; ++e) {
    const int rowe = (e & 3) + 8 * (e >> 2) + 4 * g;
    const long long av1 =
        (long long)acc10[e] + ((long long)acc11[e] << 8) + ((long long)acc12[e] << 16);
    const long long r1 = av1 >> s1v;
    const long long av3 =
        (long long)acc30[e] + ((long long)acc31[e] << 8) + ((long long)acc32[e] << 16);
    const long long r2 = av3 >> s3v;
    // Exact silu: |r1| <= 2^14 so |xf| <= 2^-9; sigma = 0.5 + xf/4 - xf^3/48,
    // truncation < 6e-17 (< 1 ulp of 0.5) -- exceeds the accuracy of the libm
    // exp path already verified bit-exact (rint margin ~4e-8).
    const double xf = (double)r1 * QINV;
    const double x2 = xf * xf;
    const double sg = 0.5 + xf * (0.25 - x2 * (1.0 / 48.0));
    const long long s1q = (long long)rint((double)r1 * sg);
    const long long gv = (s1q * r2) >> 23;
    gt[ebase + rowe * 16] = (signed char)gv;
  }
}

// ---------------- gemm2: q = (gate @ w2^T) >> s2, int32 out; 2-buf, conflict-free reads ----------------
__global__ __launch_bounds__(256, 2) void gemm2_kernel(
    const signed char* __restrict__ GATE, const signed char* __restrict__ W2T,
    int* __restrict__ out, const int* __restrict__ scale2p) {
  __shared__ __align__(16) signed char lds[32768];  // 2 bufs x (A 8192 + B 8192)
  const int tid = threadIdx.x;
  const int wv = tid >> 6;
  const int lane = tid & 63;
  const int r32 = lane & 31;
  const int g = lane >> 5;
  // XCD-grouping swizzle: 1024 blocks = 8 XCDs * 8 tm * 16 tn
  const int bi = blockIdx.x;
  const int c = bi & 7;
  const int q = bi >> 3;           // 0..127
  const int tm = (q >> 4) * 8 + c; // 0..63 (T/128)
  const int tn = q & 15;           // 0..15 (D/128)
  const int wm = wv >> 1, wn = wv & 1;

  i32x16 acc00 = zero16(), acc01 = zero16(), acc10 = zero16(), acc11 = zero16();

  auto stage = [&](int kt, int b) {
    signed char* buf = lds + b * 16384;
#pragma unroll
    for (int j = 0; j < 2; ++j) {
      const int ch = wv * 2 + j;  // 8 chunks: 2 gate m-tiles
      gld_lds16(GATE + ((size_t)((tm * 2 + (ch >> 2)) * NT_F + kt)) * 4096 + (ch & 3) * 1024 +
                    lane * 16,
                buf + ch * 1024);
    }
#pragma unroll
    for (int j = 0; j < 2; ++j) {
      const int ch = wv * 2 + j;  // 8 chunks: 2 w2 d-tiles
      gld_lds16(W2T + ((size_t)((tn * 2 + (ch >> 2)) * NT_F + kt)) * 4096 + (ch & 3) * 1024 +
                    lane * 16,
                buf + 8192 + ch * 1024);
    }
  };

  const int loff = lane * 16;

  auto compute = [&](int b) {
    const signed char* A = lds + b * 16384 + wm * 4096;
    const signed char* B = lds + b * 16384 + 8192 + wn * 4096;
#pragma unroll
    for (int kk = 0; kk < 2; ++kk) {
      const int ko = kk * 2048;
      const i32x4 a0 = *(const i32x4*)(A + ko + loff);          // rows 0-31 of wave tile
      const i32x4 a1 = *(const i32x4*)(A + ko + 1024 + loff);   // rows 32-63
      const i32x4 b0 = *(const i32x4*)(B + ko + loff);
      const i32x4 b1 = *(const i32x4*)(B + ko + 1024 + loff);
      acc00 = __builtin_amdgcn_mfma_i32_32x32x32_i8(a0, b0, acc00, 0, 0, 0);
      acc01 = __builtin_amdgcn_mfma_i32_32x32x32_i8(a0, b1, acc01, 0, 0, 0);
      acc10 = __builtin_amdgcn_mfma_i32_32x32x32_i8(a1, b0, acc10, 0, 0, 0);
      acc11 = __builtin_amdgcn_mfma_i32_32x32x32_i8(a1, b1, acc11, 0, 0, 0);
    }
  };

  stage(0, 0);

  for (int kt = 0; kt < NT_F; ++kt) {
    const int b = kt & 1;
    __syncthreads();
    if (kt + 1 < NT_F) stage(kt + 1, b ^ 1);
    compute(b);
  }

  const int s2v = scale2p[0];
  int* obase = out + (size_t)(tm * 128 + wm * 64) * DDIM + tn * 128 + wn * 64;
#pragma unroll
  for (int e = 0; e < 16; ++e) {
    const int rowe = (e & 3) + 8 * (e >> 2) + 4 * g;
    obase[(size_t)rowe * DDIM + r32] = acc00[e] >> s2v;
    obase[(size_t)rowe * DDIM + 32 + r32] = acc01[e] >> s2v;
    obase[(size_t)(rowe + 32) * DDIM + r32] = acc10[e] >> s2v;
    obase[(size_t)(rowe + 32) * DDIM + 32 + r32] = acc11[e] >> s2v;
  }
}

extern "C" void kernel_launch(void* const* d_in, const int* in_sizes, int n_in,
                              void* d_out, int out_size, void* d_ws, size_t ws_size,
                              hipStream_t stream) {
  if (n_in < 7) return;
  const int* x = (const int*)d_in[0];
  const int* w1 = (const int*)d_in[1];
  const int* w2 = (const int*)d_in[2];
  const int* w3 = (const int*)d_in[3];
  const int* s1 = (const int*)d_in[4];
  const int* s2 = (const int*)d_in[5];
  const int* s3 = (const int*)d_in[6];
  signed char* ws = (signed char*)d_ws;
  int* out = (int*)d_out;

  const size_t XD_OFF = 0;
  const size_t XD_SZ = (size_t)NT_M * NT_D * 3 * 4096;   // 50331648
  const size_t WT_SZ = (size_t)NT_F * NT_D * 4096;       // 2883584
  const size_t W1_OFF = XD_OFF + XD_SZ;
  const size_t W3_OFF = W1_OFF + WT_SZ;
  const size_t W2_OFF = W3_OFF + WT_SZ;
  const size_t GATE_OFF = W2_OFF + WT_SZ;
  const size_t GATE_SZ = (size_t)NT_M * NT_F * 4096;     // 11534336
  if (ws_size < GATE_OFF + GATE_SZ) return;  // ~70.5 MB required

  pack_x_kernel<<<dim3(NT_D, NT_M), 256, 0, stream>>>(x, ws + XD_OFF);
  pack_w_kernel<<<dim3(704, 3), 256, 0, stream>>>(w1, w3, w2, ws + W1_OFF, ws + W3_OFF,
                                                  ws + W2_OFF);
  gemm1_kernel<<<dim3(2816), 256, 0, stream>>>(ws + XD_OFF, ws + W1_OFF, ws + W3_OFF,
                                               ws + GATE_OFF, s1, s3);
  gemm2_kernel<<<dim3(1024), 256, 0, stream>>>(ws + GATE_OFF, ws + W2_OFF, out, s2);
}